// Round 1
// baseline (1721.183 us; speedup 1.0000x reference)
//
#include <hip/hip_runtime.h>
#include <math.h>

// ---- model constants ----
#define BS_TOT   1024          // B*S
#define DM       256           // d_model
#define DST      128           // d_state
#define NH       4
#define DH       32
#define TSTEPS   8
#define DECAYF   0.6065306597126334f
#define SCALEF   0.17677669529663689f   // 1/sqrt(32)

// ======================= embedding =======================
__global__ void embed_k(const int* __restrict__ ids, const float* __restrict__ emb,
                        float* __restrict__ tok) {
    int r = blockIdx.x, c = threadIdx.x;
    tok[r * DM + c] = emb[(size_t)ids[r] * DM + c];
}

// ======================= per-layer init / weight prep =======================
// grid 1024 x 256  (covers 262144)
__global__ void init_k(float* __restrict__ h, float* __restrict__ sv, float* __restrict__ ov,
                       float* __restrict__ W1, float* __restrict__ B1,
                       const float* __restrict__ Al, const float* __restrict__ Wql,
                       const float* __restrict__ bql, float* __restrict__ state) {
    int i = blockIdx.x * 256 + threadIdx.x;
    if (i < BS_TOT * DST) { h[i] = 0.f; sv[i] = 0.f; }
    ov[i] = 0.f;                                   // grid is exactly 262144
    if (i < 256 * 128) {
        int c = i >> 7;
        int kk = i & 127;
        W1[i] = (c < 128) ? Al[i] : Wql[(c - 128) * 128 + kk];
    }
    if (i < 256) B1[i] = (i < 128) ? 0.f : bql[i - 128];
    if (i == 0) {
        state[0] = 1.0f;   // ts
        state[1] = 1.0f;   // to
        ((int*)(state + 2))[0] = 0;  // cnt1
        ((int*)(state + 2))[1] = 0;  // cnt2
    }
}

// ======================= time-mean =======================
__global__ void mean_k(const float* __restrict__ outs, float* __restrict__ ti) {
    int i = blockIdx.x * 256 + threadIdx.x;
    float s = 0.f;
#pragma unroll
    for (int t = 0; t < TSTEPS; ++t) s += outs[t * (BS_TOT * DM) + i];
    ti[i] = s * 0.125f;
}

// ======================= generic fp32 GEMM (+ LIF epilogues) =======================
// C[M,N] = A[M,K] @ W[N,K]^T (+bias)(+add) with optional LIF epilogue.
#define MODE_PLAIN 0
#define MODE_LIF1  1
#define MODE_LIF2  2

template <int BM, int BN, int BK, int TM, int TN, int MODE>
__global__ __launch_bounds__((BM / TM) * (BN / TN))
void gemm_k(const float* __restrict__ Amat, const float* __restrict__ Wmat,
            const float* __restrict__ bias, float* __restrict__ outp,
            int M, int N, int K,
            const float* __restrict__ add, int add_ld,
            float* __restrict__ vst, float* __restrict__ spk,
            const float* __restrict__ thr_use, int* __restrict__ cnt_add,
            float* __restrict__ thr_upd, int* __restrict__ cnt_src,
            float inv_n, int do_upd) {
    constexpr int NT  = (BM / TM) * (BN / TN);
    constexpr int NXT = BN / TN;
    __shared__ float As[BK][BM + 4];
    __shared__ float Bs[BK][BN + 4];
    const int tid = threadIdx.x;
    const int n0 = blockIdx.x * BN, m0 = blockIdx.y * BM;
    const int tx = tid % NXT, ty = tid / NXT;
    float acc[TM][TN] = {};

    for (int k0 = 0; k0 < K; k0 += BK) {
#pragma unroll
        for (int i = 0; i < (BM * BK) / NT; ++i) {
            int idx = i * NT + tid;
            int kk = idx % BK, mm = idx / BK;
            As[kk][mm] = Amat[(size_t)(m0 + mm) * K + k0 + kk];
        }
#pragma unroll
        for (int i = 0; i < (BN * BK) / NT; ++i) {
            int idx = i * NT + tid;
            int kk = idx % BK, nn = idx / BK;
            Bs[kk][nn] = Wmat[(size_t)(n0 + nn) * K + k0 + kk];
        }
        __syncthreads();
#pragma unroll
        for (int kk = 0; kk < BK; ++kk) {
            float a[TM], b[TN];
#pragma unroll
            for (int i = 0; i < TM; ++i) a[i] = As[kk][ty * TM + i];
#pragma unroll
            for (int j = 0; j < TN; ++j) b[j] = Bs[kk][tx * TN + j];
#pragma unroll
            for (int i = 0; i < TM; ++i)
#pragma unroll
                for (int j = 0; j < TN; ++j) acc[i][j] += a[i] * b[j];
        }
        __syncthreads();
    }

    int my_cnt = 0;
#pragma unroll
    for (int i = 0; i < TM; ++i) {
        int mr = m0 + ty * TM + i;
#pragma unroll
        for (int j = 0; j < TN; ++j) {
            int nc = n0 + tx * TN + j;
            float x = acc[i][j];
            if (MODE == MODE_PLAIN) {
                if (bias) x += bias[nc];
                outp[(size_t)mr * N + nc] = x;
            } else {
                if (bias) x += bias[nc];
                if (add)  x += add[(size_t)mr * add_ld + nc];
                float v  = vst[(size_t)mr * N + nc];
                float vp = v * DECAYF + x;
                float thr = *thr_use;
                float sp = (vp - thr >= 0.f) ? 1.f : 0.f;
                spk[(size_t)mr * N + nc] = sp;
                vst[(size_t)mr * N + nc] = vp * (1.f - sp);
                my_cnt += (int)sp;
            }
        }
    }
    if (MODE != MODE_PLAIN) {
#pragma unroll
        for (int off = 32; off > 0; off >>= 1) my_cnt += __shfl_down(my_cnt, off, 64);
        if ((tid & 63) == 0) atomicAdd(cnt_add, my_cnt);
        if (blockIdx.x == 0 && blockIdx.y == 0 && tid == 0 && do_upd) {
            float e  = (float)(*cnt_src) * inv_n - 0.02f;
            float nt = *thr_upd + 0.1f * e;
            *thr_upd = fmaxf(nt, 0.5f);
            *cnt_src = 0;
        }
    }
}

// ======================= attention =======================
// grid = 4 heads * 128 row-tiles = 512 blocks, 256 threads.
// Block: 8 query rows of one head, full 1024-key two-pass softmax attention.
#define AT_ROWS 8
__global__ __launch_bounds__(256)
void attn_k(const float* __restrict__ stq,   // q at [m*256 + 128 + hd*32 + d]
            const float* __restrict__ kv,    // k at [b*256 + hd*32 + d], v at +128
            float* __restrict__ att) {       // [1024 x 128]
    __shared__ float s_s[AT_ROWS][1026];
    __shared__ float kv_s[32][66];
    __shared__ float red[AT_ROWS][33];
    __shared__ float mrow[AT_ROWS], linv[AT_ROWS];

    const int tid = threadIdx.x;
    const int hd = blockIdx.x >> 7;
    const int r0 = (blockIdx.x & 127) * AT_ROWS;
    const int rA = tid >> 5;        // 0..7
    const int lg = tid & 31;        // 0..31

    // q row into registers
    float qreg[32];
    {
        const float* qp = stq + (size_t)(r0 + rA) * DM + 128 + hd * 32;
#pragma unroll
        for (int d = 0; d < 32; ++d) qreg[d] = qp[d];
    }

    // ---- phase A: scores ----
    for (int c = 0; c < 16; ++c) {
#pragma unroll
        for (int i = 0; i < 8; ++i) {
            int idx = i * 256 + tid;
            int key = idx >> 5, d = idx & 31;
            kv_s[d][key] = kv[(size_t)(c * 64 + key) * DM + hd * 32 + d];
        }
        __syncthreads();
        float s0 = 0.f, s1 = 0.f;
#pragma unroll
        for (int d = 0; d < 32; ++d) {
            float qd = qreg[d];
            s0 += qd * kv_s[d][lg];
            s1 += qd * kv_s[d][lg + 32];
        }
        s_s[rA][c * 64 + lg]      = s0 * SCALEF;
        s_s[rA][c * 64 + lg + 32] = s1 * SCALEF;
        __syncthreads();
    }

    // ---- softmax (two-pass over the stored 1024 scores) ----
    {
        float mx = -1e30f;
        for (int j = 0; j < 32; ++j) mx = fmaxf(mx, s_s[rA][lg + 32 * j]);
        red[rA][lg] = mx;
        __syncthreads();
        if (tid < AT_ROWS) {
            float m = red[tid][0];
            for (int j = 1; j < 32; ++j) m = fmaxf(m, red[tid][j]);
            mrow[tid] = m;
        }
        __syncthreads();
        float m = mrow[rA];
        float ls = 0.f;
        for (int j = 0; j < 32; ++j) {
            float p = expf(s_s[rA][lg + 32 * j] - m);
            s_s[rA][lg + 32 * j] = p;
            ls += p;
        }
        red[rA][lg] = ls;
        __syncthreads();
        if (tid < AT_ROWS) {
            float l = 0.f;
            for (int j = 0; j < 32; ++j) l += red[tid][j];
            linv[tid] = 1.0f / l;
        }
        __syncthreads();
    }

    // ---- phase B: P @ V.  thread owns (row rA, dim lg) ----
    float acc = 0.f;
    for (int c = 0; c < 16; ++c) {
#pragma unroll
        for (int i = 0; i < 8; ++i) {
            int idx = i * 256 + tid;
            int key = idx >> 5, d = idx & 31;
            kv_s[d][key] = kv[(size_t)(c * 64 + key) * DM + 128 + hd * 32 + d];
        }
        __syncthreads();
#pragma unroll
        for (int j = 0; j < 64; ++j)
            acc += s_s[rA][c * 64 + j] * kv_s[lg][j];
        __syncthreads();
    }
    att[(size_t)(r0 + rA) * DST + hd * 32 + lg] = acc * linv[rA];
}

// ======================= host =======================
extern "C" void kernel_launch(void* const* d_in, const int* in_sizes, int n_in,
                              void* d_out, int out_size, void* d_ws, size_t ws_size,
                              hipStream_t stream) {
    const int*   ids  = (const int*)d_in[0];
    const float* emb  = (const float*)d_in[1];
    const float* Aw   = (const float*)d_in[2];
    const float* Cw   = (const float*)d_in[3];
    const float* Wq   = (const float*)d_in[4];
    const float* bq   = (const float*)d_in[5];
    const float* Wkv  = (const float*)d_in[6];
    const float* bkv  = (const float*)d_in[7];
    const float* Wo   = (const float*)d_in[8];
    const float* bo   = (const float*)d_in[9];
    const float* Wout = (const float*)d_in[10];
    const float* bout = (const float*)d_in[11];
    float* out = (float*)d_out;
    float* ws  = (float*)d_ws;

    const int NE = BS_TOT * DM;       // 262144
    float* tok  = ws;                 // 262144
    float* bufA = tok  + NE;          // 8*262144
    float* bufB = bufA + 8 * NE;      // 8*262144
    float* kvb  = bufB + 8 * NE;      // 8*262144
    float* stq  = kvb  + 8 * NE;      // 262144
    float* att  = stq  + NE;          // 131072
    float* hbuf = att  + BS_TOT * DST;
    float* sv   = hbuf + BS_TOT * DST;
    float* ov   = sv   + BS_TOT * DST;
    float* ti   = ov   + NE;          // 262144
    float* W1   = ti   + NE;          // 32768
    float* B1   = W1   + 32768;       // 256
    float* state = B1 + 256;          // [ts, to, cnt1(int), cnt2(int)]
    int* cnts = (int*)(state + 2);

    embed_k<<<dim3(1024), dim3(256), 0, stream>>>(ids, emb, tok);

    for (int l = 0; l < 2; ++l) {
        const float* Al   = Aw  + l * 16384;
        const float* Cl   = Cw  + l * 32768;
        const float* Wql  = Wq  + l * 16384;
        const float* bql  = bq  + l * 128;
        const float* Wkvl = Wkv + l * 65536;
        const float* bkvl = bkv + l * 256;
        const float* Wol  = Wo  + l * 16384;
        const float* bol  = bo  + l * 128;
        const float* xin  = (l == 0) ? tok : bufA;
        float* outs       = (l == 0) ? bufA : bufB;
        int Mkv           = (l == 0) ? BS_TOT : 8 * BS_TOT;

        init_k<<<dim3(1024), dim3(256), 0, stream>>>(hbuf, sv, ov, W1, B1, Al, Wql, bql, state);

        // kv for the whole layer (x is known up-front)
        gemm_k<32,32,16,4,4,MODE_PLAIN><<<dim3(256/32, Mkv/32), dim3(64), 0, stream>>>(
            xin, Wkvl, bkvl, kvb, Mkv, 256, 256,
            nullptr, 0, nullptr, nullptr, nullptr, nullptr, nullptr, nullptr, 0.f, 0);

        for (int t = 0; t < TSTEPS; ++t) {
            const float* kvt = (l == 0) ? kvb : kvb + (size_t)t * NE;

            // stq = h @ [A;Wq]^T + [0;bq]
            gemm_k<32,32,16,4,4,MODE_PLAIN><<<dim3(8, 32), dim3(64), 0, stream>>>(
                hbuf, W1, B1, stq, BS_TOT, 256, 128,
                nullptr, 0, nullptr, nullptr, nullptr, nullptr, nullptr, nullptr, 0.f, 0);

            attn_k<<<dim3(512), dim3(256), 0, stream>>>(stq, kvt, att);

            // upd = st + att@Wo^T + bo -> LIF1 -> h (spikes), sv; count->cnt1; update `to` from cnt2 (t>0)
            gemm_k<32,32,16,4,4,MODE_LIF1><<<dim3(4, 32), dim3(64), 0, stream>>>(
                att, Wol, bol, nullptr, BS_TOT, 128, 128,
                stq, 256, sv, hbuf, &state[0], &cnts[0],
                &state[1], &cnts[1], 1.f / 262144.f, (t > 0) ? 1 : 0);

            // out_pot = h@C^T -> LIF2 -> outs[t], ov; count->cnt2; update `ts` from cnt1
            gemm_k<32,32,16,4,4,MODE_LIF2><<<dim3(8, 32), dim3(64), 0, stream>>>(
                hbuf, Cl, nullptr, nullptr, BS_TOT, 256, 128,
                nullptr, 0, ov, outs + (size_t)t * NE, &state[1], &cnts[1],
                &state[0], &cnts[0], 1.f / 131072.f, 1);
        }
    }

    mean_k<<<dim3(1024), dim3(256), 0, stream>>>(bufB, ti);

    // logits = ti @ Wout^T + bout
    gemm_k<64,64,16,4,4,MODE_PLAIN><<<dim3(32000/64, BS_TOT/64), dim3(256), 0, stream>>>(
        ti, Wout, bout, out, BS_TOT, 32000, 256,
        nullptr, 0, nullptr, nullptr, nullptr, nullptr, nullptr, nullptr, 0.f, 0);
}